// Round 11
// baseline (2195.428 us; speedup 1.0000x reference)
//
#include <hip/hip_runtime.h>
#include <stdint.h>

#define DIM 64
#define GB 128          // nodes per dst-bucket (NB = ceil(N/GB) must be <= 1024)
#define GSH 7
#define CH 4096         // edges per partition block (391 blocks @ E=1.6M)
#define TB1 256
#define HW 25000        // u8 hist words: 100000 bins / 4 per u32 (100 KB LDS)
#define NSL 256         // edge slices for src hist (256 blocks = 1/CU)
#define TBH 1024        // hist block size

// bf16 helpers: RNE pack, shift-unpack
__device__ __forceinline__ unsigned bf16rne(float f) {
    unsigned u = __float_as_uint(f);
    return (u + 0x7FFFu + ((u >> 16) & 1u)) >> 16;
}
__device__ __forceinline__ unsigned pack2(float lo, float hi) {
    return bf16rne(lo) | (bf16rne(hi) << 16);
}
#define UNPK(u, lo, hi) { lo = __uint_as_float((u) << 16); hi = __uint_as_float((u) & 0xFFFF0000u); }

// ---- outdeg histogram: u8x4-packed LDS + per-slice dst-bucket counts ----
__global__ void __launch_bounds__(TBH)
hist_kernel(const int* __restrict__ src, const int* __restrict__ dst,
            unsigned* __restrict__ partials, int* __restrict__ bslice,
            int E, int N, int Es, int NB) {
    __shared__ unsigned h8[HW];   // 100 KB: 4 u8 counters per word
    __shared__ int hb[1024];
    const int s = blockIdx.x;
    const int nw = (N + 3) >> 2;
    for (int j = threadIdx.x; j < nw; j += TBH) h8[j] = 0;
    for (int j = threadIdx.x; j < 1024; j += TBH) hb[j] = 0;
    __syncthreads();
    const int e0 = s * Es, e1 = min(e0 + Es, E);
#pragma unroll 4
    for (int i = e0 + threadIdx.x; i < e1; i += TBH) {
        unsigned sj = (unsigned)src[i];
        unsigned tj = (unsigned)dst[i];
        atomicAdd(&h8[sj >> 2], 1u << ((sj & 3) * 8));
        atomicAdd(&hb[tj >> GSH], 1);
    }
    __syncthreads();
    unsigned* part = partials + (size_t)s * nw;
    for (int j = threadIdx.x; j < nw; j += TBH) part[j] = h8[j];
    for (int j = threadIdx.x; j < NB; j += TBH) bslice[s * 1024 + j] = hb[j];
}

// ---- merge u8 partials -> dis (128-thread blocks for CU coverage) -------
__global__ void __launch_bounds__(128)
merge_dis(const unsigned* __restrict__ partials, float* __restrict__ dis,
          int nw, int N) {
    const int w = blockIdx.x * 128 + threadIdx.x;
    if (w >= nw) return;
    int s0 = 0, s1 = 0, s2 = 0, s3 = 0;
#pragma unroll 8
    for (int s = 0; s < NSL; ++s) {
        unsigned v = partials[(size_t)s * nw + w];
        s0 += v & 255u; s1 += (v >> 8) & 255u;
        s2 += (v >> 16) & 255u; s3 += v >> 24;
    }
    const int nidx = w * 4;
    if (nidx + 3 < N) {
        *(float4*)(dis + nidx) = make_float4(
            rsqrtf((float)s0 + 1.f), rsqrtf((float)s1 + 1.f),
            rsqrtf((float)s2 + 1.f), rsqrtf((float)s3 + 1.f));
    } else {
        if (nidx + 0 < N) dis[nidx + 0] = rsqrtf((float)s0 + 1.f);
        if (nidx + 1 < N) dis[nidx + 1] = rsqrtf((float)s1 + 1.f);
        if (nidx + 2 < N) dis[nidx + 2] = rsqrtf((float)s2 + 1.f);
        if (nidx + 3 < N) dis[nidx + 3] = rsqrtf((float)s3 + 1.f);
    }
}

// ---- single block: sum bslice + exclusive scan -> bucket_base/cursor ----
__global__ void scan_buckets(const int* __restrict__ bslice, int* __restrict__ bucket_base,
                             int* __restrict__ cursor, int NB) {
    __shared__ int buf[1024];
    const int t = threadIdx.x;
    int v = 0;
    if (t < NB)
        for (int s = 0; s < NSL; ++s) v += bslice[s * 1024 + t];
    buf[t] = v;
    __syncthreads();
    for (int off = 1; off < 1024; off <<= 1) {
        int add = (t >= off) ? buf[t - off] : 0;
        __syncthreads();
        buf[t] += add;
        __syncthreads();
    }
    if (t < NB) { bucket_base[t] = buf[t] - v; cursor[t] = buf[t] - v; }
    if (t == NB - 1) bucket_base[NB] = buf[t];
}

// ---- partition edges into dst-bucket-major records + fused z0 build -----
// Record = (src | tl<<20, raw ew). No dis anywhere: the norm factors as
// y[t] = dis[t]*(sum ew*z[s] + z[t]) with z = dis .* x, so records carry
// only ew and staged IS the final edge structure (place kernel deleted).
// Conv rider blocks build z0 = bf16(dis .* emb).
__global__ void __launch_bounds__(TB1)
part_conv_kernel(const int* __restrict__ src, const int* __restrict__ dst,
                 const float* __restrict__ ew,
                 int* __restrict__ cursor, int2* __restrict__ staged,
                 const float4* __restrict__ emb4, const float* __restrict__ dis,
                 uint4* __restrict__ z0,
                 int E, int NB, int npart, int n8) {
    __shared__ int h[1024];
    if ((int)blockIdx.x >= npart) {
        const int i = (blockIdx.x - npart) * TB1 + threadIdx.x;
        if (i >= n8) return;
        const float dn = dis[i >> 3];
        float4 a = emb4[2 * i], b = emb4[2 * i + 1];
        uint4 o;
        o.x = pack2(dn * a.x, dn * a.y); o.y = pack2(dn * a.z, dn * a.w);
        o.z = pack2(dn * b.x, dn * b.y); o.w = pack2(dn * b.z, dn * b.w);
        z0[i] = o;
        return;
    }
    const int tid = threadIdx.x;
    const int e0 = blockIdx.x * CH;
    const int e1 = min(e0 + CH, E);
    for (int j = tid; j < 1024; j += TB1) h[j] = 0;
    __syncthreads();
    int4 d[CH / (TB1 * 4)];
    int ngrp = 0;
    for (int i = e0 + tid * 4, k = 0; i < e1; i += TB1 * 4, ++k) {
        int4 t;
        if (i + 3 < e1) t = *(const int4*)(dst + i);
        else {
            t.x = dst[i];
            t.y = (i + 1 < e1) ? dst[i + 1] : -1;
            t.z = (i + 2 < e1) ? dst[i + 2] : -1;
            t.w = (i + 3 < e1) ? dst[i + 3] : -1;
        }
        d[k] = t;
        if (t.x >= 0) atomicAdd(&h[t.x >> GSH], 1);
        if (t.y >= 0) atomicAdd(&h[t.y >> GSH], 1);
        if (t.z >= 0) atomicAdd(&h[t.z >> GSH], 1);
        if (t.w >= 0) atomicAdd(&h[t.w >> GSH], 1);
        ngrp = k + 1;
    }
    __syncthreads();
    for (int j = tid; j < NB; j += TB1) {
        int c = h[j];
        h[j] = c ? atomicAdd(&cursor[j], c) : 0;
    }
    __syncthreads();
    for (int i = e0 + tid * 4, k = 0; k < ngrp; i += TB1 * 4, ++k) {
        int4 t = d[k];
        int4 ss = make_int4(0, 0, 0, 0);
        float4 ww = make_float4(0.f, 0.f, 0.f, 0.f);
        if (i + 3 < e1) { ss = *(const int4*)(src + i); ww = *(const float4*)(ew + i); }
        else {
            ss.x = src[i]; ww.x = ew[i];
            if (i + 1 < e1) { ss.y = src[i + 1]; ww.y = ew[i + 1]; }
            if (i + 2 < e1) { ss.z = src[i + 2]; ww.z = ew[i + 2]; }
            if (i + 3 < e1) { ss.w = src[i + 3]; ww.w = ew[i + 3]; }
        }
#define PART1(T, S, W) if ((T) >= 0) { \
        int pos_ = atomicAdd(&h[(T) >> GSH], 1); \
        staged[pos_] = make_int2((S) | (((T) & (GB - 1)) << 20), __float_as_int(W)); }
        PART1(t.x, ss.x, ww.x)
        PART1(t.y, ss.y, ww.y)
        PART1(t.z, ss.z, ww.z)
        PART1(t.w, ss.w, ww.w)
#undef PART1
    }
}

// ---- bucket propagation: block = 1 bucket, LDS f32 accumulator ----------
// Streams the bucket's (unsorted) records; wave handles 8 records at a
// time, 8 lanes/record each gathering 16 B of the 128-B z row; ds_add_f32
// into acc[tl][d] (stride 65 -> ~2-way banks, free). Epilogue:
//   y = dis[t]*(acc + z_self);  store y (bf16, combine) + z_next=dis*y.
// MODE 2 fuses the final combine: out = 0.25*(emb + y1 + y2 + y3).
template<int MODE>
__global__ void __launch_bounds__(256)
bprop(const uint4* __restrict__ zin, const int2* __restrict__ staged,
      const int* __restrict__ bucket_base, const float* __restrict__ dis,
      uint4* __restrict__ ystore, uint4* __restrict__ zstore,
      const float4* __restrict__ embF, const uint4* __restrict__ y1F,
      const uint4* __restrict__ y2F, float4* __restrict__ outF, int N) {
    __shared__ float acc[GB * 65];   // 33.3 KB
    __shared__ float disb[GB];
    const int b = blockIdx.x;
    const int n0 = b << GSH;
    const int nb = min(GB, N - n0);
    const int r0 = bucket_base[b], r1 = bucket_base[b + 1];
    for (int j = threadIdx.x; j < GB * 65; j += 256) acc[j] = 0.f;
    if (threadIdx.x < nb) disb[threadIdx.x] = dis[n0 + threadIdx.x];
    __syncthreads();
    const int lane = threadIdx.x & 63;
    const int fl = lane & 7, sub = lane >> 3;
    const int wid = threadIdx.x >> 6;

#define GATH(IDX, REC, Q, W) { \
    bool v_ = (IDX) < r1; \
    REC = v_ ? staged[IDX] : make_int2(0, 0); \
    W = v_ ? __int_as_float(REC.y) : 0.f; \
    Q = v_ ? zin[(size_t)(REC.x & 0xFFFFF) * 8 + fl] : make_uint4(0, 0, 0, 0); }
#define ACCUM(REC, Q, W) { \
    float* a_ = &acc[((REC.x >> 20) & (GB - 1)) * 65 + fl * 8]; \
    float l, h; \
    UNPK(Q.x, l, h) atomicAdd(a_ + 0, W * l); atomicAdd(a_ + 1, W * h); \
    UNPK(Q.y, l, h) atomicAdd(a_ + 2, W * l); atomicAdd(a_ + 3, W * h); \
    UNPK(Q.z, l, h) atomicAdd(a_ + 4, W * l); atomicAdd(a_ + 5, W * h); \
    UNPK(Q.w, l, h) atomicAdd(a_ + 6, W * l); atomicAdd(a_ + 7, W * h); }

    for (int pb = r0 + wid * 16; pb < r1; pb += 64) {
        int2 rA, rB; uint4 qA, qB; float wA, wB;
        GATH(pb + sub, rA, qA, wA)
        GATH(pb + 8 + sub, rB, qB, wB)
        ACCUM(rA, qA, wA)
        ACCUM(rB, qB, wB)
    }
#undef GATH
#undef ACCUM
    __syncthreads();

    const int tl2 = threadIdx.x >> 1, h2 = threadIdx.x & 1;
    if (tl2 >= nb) return;
    const float dn = disb[tl2];
    const size_t base = (size_t)(n0 + tl2) * 8 + h2 * 4;
    const float* a = &acc[tl2 * 65 + h2 * 32];
    if (MODE < 2) {
#pragma unroll
        for (int k = 0; k < 4; ++k) {
            uint4 zs = zin[base + k];
            float l, h, y0, y1v, y2v, y3v, y4v, y5v, y6v, y7v;
            UNPK(zs.x, l, h) y0  = dn * (a[k*8+0] + l); y1v = dn * (a[k*8+1] + h);
            UNPK(zs.y, l, h) y2v = dn * (a[k*8+2] + l); y3v = dn * (a[k*8+3] + h);
            UNPK(zs.z, l, h) y4v = dn * (a[k*8+4] + l); y5v = dn * (a[k*8+5] + h);
            UNPK(zs.w, l, h) y6v = dn * (a[k*8+6] + l); y7v = dn * (a[k*8+7] + h);
            uint4 yo, zo;
            yo.x = pack2(y0, y1v);  yo.y = pack2(y2v, y3v);
            yo.z = pack2(y4v, y5v); yo.w = pack2(y6v, y7v);
            zo.x = pack2(dn * y0, dn * y1v);   zo.y = pack2(dn * y2v, dn * y3v);
            zo.z = pack2(dn * y4v, dn * y5v);  zo.w = pack2(dn * y6v, dn * y7v);
            ystore[base + k] = yo;
            zstore[base + k] = zo;
        }
    } else {
#pragma unroll
        for (int k = 0; k < 4; ++k) {
            uint4 zs = zin[base + k];
            uint4 q1 = y1F[base + k], q2 = y2F[base + k];
            float4 eA = embF[(size_t)(n0 + tl2) * 16 + h2 * 8 + k * 2];
            float4 eB = embF[(size_t)(n0 + tl2) * 16 + h2 * 8 + k * 2 + 1];
            float l, h;
            float r0v, r1v, r2v, r3v, r4v, r5v, r6v, r7v;
            UNPK(zs.x, l, h) r0v = dn * (a[k*8+0] + l); r1v = dn * (a[k*8+1] + h);
            UNPK(zs.y, l, h) r2v = dn * (a[k*8+2] + l); r3v = dn * (a[k*8+3] + h);
            UNPK(zs.z, l, h) r4v = dn * (a[k*8+4] + l); r5v = dn * (a[k*8+5] + h);
            UNPK(zs.w, l, h) r6v = dn * (a[k*8+6] + l); r7v = dn * (a[k*8+7] + h);
            UNPK(q1.x, l, h) r0v += l; r1v += h;
            UNPK(q1.y, l, h) r2v += l; r3v += h;
            UNPK(q1.z, l, h) r4v += l; r5v += h;
            UNPK(q1.w, l, h) r6v += l; r7v += h;
            UNPK(q2.x, l, h) r0v += l; r1v += h;
            UNPK(q2.y, l, h) r2v += l; r3v += h;
            UNPK(q2.z, l, h) r4v += l; r5v += h;
            UNPK(q2.w, l, h) r6v += l; r7v += h;
            r0v += eA.x; r1v += eA.y; r2v += eA.z; r3v += eA.w;
            r4v += eB.x; r5v += eB.y; r6v += eB.z; r7v += eB.w;
            outF[(size_t)(n0 + tl2) * 16 + h2 * 8 + k * 2] =
                make_float4(0.25f * r0v, 0.25f * r1v, 0.25f * r2v, 0.25f * r3v);
            outF[(size_t)(n0 + tl2) * 16 + h2 * 8 + k * 2 + 1] =
                make_float4(0.25f * r4v, 0.25f * r5v, 0.25f * r6v, 0.25f * r7v);
        }
    }
}

// ---- launch -------------------------------------------------------------

extern "C" void kernel_launch(void* const* d_in, const int* in_sizes, int n_in,
                              void* d_out, int out_size, void* d_ws, size_t ws_size,
                              hipStream_t stream) {
    const float* emb = (const float*)d_in[0];   // [N, 64] fp32
    const float* ew  = (const float*)d_in[1];   // [E] fp32
    const int*   ei  = (const int*)d_in[2];     // [2, E] int32
    const int E = in_sizes[2] / 2;
    const int N = in_sizes[0] / DIM;
    const int* src = ei;        // edge_index[0] = source j
    const int* dst = ei + E;    // edge_index[1] = target i
    float* out = (float*)d_out;

    const int NB = (N + GB - 1) >> GSH;   // dst buckets (782 @ N=100k)
    const int Es = (E + NSL - 1) / NSL;   // edges per hist slice
    const int nw = (N + 3) >> 2;          // u8 hist words per slice

    // workspace (~79 MB). Alias: partials (25.6 MB, dead after merge_dis/
    // scan) -> staged (12.8 MB, live to end). z2 aliases z0 (z0 dead after
    // bprop<0>; z2 written by bprop<1>).
    char* w = (char*)d_ws;
    size_t xSz = ((size_t)N * DIM * 2 + 255) & ~(size_t)255;       // 12.8 MB
    size_t sSz = ((size_t)E * 8 + 255) & ~(size_t)255;             // 12.8 MB
    size_t pSz = ((size_t)NSL * nw * 4 + 255) & ~(size_t)255;      // 25.6 MB
    size_t uSz = pSz > sSz ? pSz : sSz;
    unsigned* partials = (unsigned*)w;
    int2* staged = (int2*)w; w += uSz;
    uint4* z0    = (uint4*)w; w += xSz;   // z0 table; reused as z2
    uint4* z1    = (uint4*)w; w += xSz;
    uint4* y1    = (uint4*)w; w += xSz;
    uint4* y2    = (uint4*)w; w += xSz;
    float* dis   = (float*)w; w += ((size_t)N * 4 + 255) & ~(size_t)255;
    int* bslice      = (int*)w; w += (size_t)NSL * 1024 * 4;   // 1 MB
    int* bucket_base = (int*)w; w += 1025 * 4;
    int* cursor      = (int*)w; w += 1024 * 4;

    hist_kernel<<<NSL, TBH, 0, stream>>>(src, dst, partials, bslice, E, N, Es, NB);
    merge_dis<<<(nw + 127) / 128, 128, 0, stream>>>(partials, dis, nw, N);
    scan_buckets<<<1, 1024, 0, stream>>>(bslice, bucket_base, cursor, NB);

    const int n8 = N * DIM / 8;
    const int npart = (E + CH - 1) / CH;
    const int nconv = (n8 + TB1 - 1) / TB1;
    part_conv_kernel<<<npart + nconv, TB1, 0, stream>>>(src, dst, ew, cursor, staged,
                                                        (const float4*)emb, dis, z0,
                                                        E, NB, npart, n8);

    bprop<0><<<NB, 256, 0, stream>>>(z0, staged, bucket_base, dis, y1, z1,
                                     nullptr, nullptr, nullptr, nullptr, N);
    bprop<1><<<NB, 256, 0, stream>>>(z1, staged, bucket_base, dis, y2, z0,
                                     nullptr, nullptr, nullptr, nullptr, N);
    bprop<2><<<NB, 256, 0, stream>>>(z0, staged, bucket_base, dis, nullptr, nullptr,
                                     (const float4*)emb, y1, y2, (float4*)out, N);
}

// Round 12
// 263.123 us; speedup vs baseline: 8.3437x; 8.3437x over previous
//
#include <hip/hip_runtime.h>
#include <stdint.h>

#define DIM 64
#define GB 256          // nodes per dst-bucket (NB = ceil(N/GB) must be <= 512)
#define GSH 8
#define CH 4096         // edges per partition block (391 blocks @ E=1.6M)
#define TB1 256
#define HW 25000        // u8 hist words: 100000 bins / 4 per u32 (100 KB LDS)
#define NSL 256         // edge slices for src hist (256 blocks = 1/CU)
#define TBH 1024        // hist block size

// bf16 helpers: RNE pack, shift-unpack
__device__ __forceinline__ unsigned bf16rne(float f) {
    unsigned u = __float_as_uint(f);
    return (u + 0x7FFFu + ((u >> 16) & 1u)) >> 16;
}
__device__ __forceinline__ unsigned pack2(float lo, float hi) {
    return bf16rne(lo) | (bf16rne(hi) << 16);
}
#define UNPK(u, lo, hi) { lo = __uint_as_float((u) << 16); hi = __uint_as_float((u) & 0xFFFF0000u); }

// ---- outdeg histogram: u8x4-packed LDS, single range, one pass ----------
__global__ void __launch_bounds__(TBH)
hist_kernel(const int* __restrict__ src, const int* __restrict__ dst,
            unsigned* __restrict__ partials, int* __restrict__ bslice,
            int E, int N, int Es, int NB) {
    __shared__ unsigned h8[HW];   // 100 KB: 4 u8 counters per word
    __shared__ int hb[512];
    const int s = blockIdx.x;
    const int nw = (N + 3) >> 2;
    for (int j = threadIdx.x; j < nw; j += TBH) h8[j] = 0;
    for (int j = threadIdx.x; j < 512; j += TBH) hb[j] = 0;
    __syncthreads();
    const int e0 = s * Es, e1 = min(e0 + Es, E);
#pragma unroll 4
    for (int i = e0 + threadIdx.x; i < e1; i += TBH) {
        unsigned sj = (unsigned)src[i];
        unsigned tj = (unsigned)dst[i];
        atomicAdd(&h8[sj >> 2], 1u << ((sj & 3) * 8));
        atomicAdd(&hb[tj >> GSH], 1);
    }
    __syncthreads();
    unsigned* part = partials + (size_t)s * nw;
    for (int j = threadIdx.x; j < nw; j += TBH) part[j] = h8[j];
    for (int j = threadIdx.x; j < NB; j += TBH) bslice[s * 512 + j] = hb[j];
}

// ---- fused: merge u8 partials -> dis  |  last block: bucket scan --------
__global__ void __launch_bounds__(512)
merge_scan_kernel(const unsigned* __restrict__ partials, const int* __restrict__ bslice,
                  float* __restrict__ dis, int* __restrict__ bucket_base,
                  int* __restrict__ cursor, int* __restrict__ offsets,
                  int nw, int nmerge, int N, int NB) {
    __shared__ int buf[512];
    if ((int)blockIdx.x < nmerge) {
        const int w = blockIdx.x * 512 + threadIdx.x;
        if (w >= nw) return;
        int s0 = 0, s1 = 0, s2 = 0, s3 = 0;
#pragma unroll 8
        for (int s = 0; s < NSL; ++s) {
            unsigned v = partials[(size_t)s * nw + w];
            s0 += v & 255u; s1 += (v >> 8) & 255u;
            s2 += (v >> 16) & 255u; s3 += v >> 24;
        }
        const int nidx = w * 4;
        if (nidx + 3 < N) {
            *(float4*)(dis + nidx) = make_float4(
                rsqrtf((float)s0 + 1.f), rsqrtf((float)s1 + 1.f),
                rsqrtf((float)s2 + 1.f), rsqrtf((float)s3 + 1.f));
        } else {
            if (nidx + 0 < N) dis[nidx + 0] = rsqrtf((float)s0 + 1.f);
            if (nidx + 1 < N) dis[nidx + 1] = rsqrtf((float)s1 + 1.f);
            if (nidx + 2 < N) dis[nidx + 2] = rsqrtf((float)s2 + 1.f);
            if (nidx + 3 < N) dis[nidx + 3] = rsqrtf((float)s3 + 1.f);
        }
    } else {
        const int t = threadIdx.x;
        int v = 0;
        if (t < NB)
            for (int s = 0; s < NSL; ++s) v += bslice[s * 512 + t];
        buf[t] = v;
        __syncthreads();
        for (int off = 1; off < 512; off <<= 1) {
            int add = (t >= off) ? buf[t - off] : 0;
            __syncthreads();
            buf[t] += add;
            __syncthreads();
        }
        if (t < NB) { bucket_base[t] = buf[t] - v; cursor[t] = buf[t] - v; }
        if (t == NB - 1) { bucket_base[NB] = buf[t]; offsets[N] = buf[t]; }
    }
}

// ---- phase 1: partition edges + fused fp32->bf16 emb conversion ---------
__global__ void __launch_bounds__(TB1)
part_conv_kernel(const int* __restrict__ src, const int* __restrict__ dst,
                 const float* __restrict__ ew,
                 int* __restrict__ cursor, int2* __restrict__ staged,
                 const float4* __restrict__ emb4, uint4* __restrict__ x0c,
                 int E, int NB, int npart, int n8) {
    __shared__ int h[512];
    if ((int)blockIdx.x >= npart) {
        const int i = (blockIdx.x - npart) * TB1 + threadIdx.x;
        if (i >= n8) return;
        float4 a = emb4[2 * i], b = emb4[2 * i + 1];
        uint4 o;
        o.x = pack2(a.x, a.y); o.y = pack2(a.z, a.w);
        o.z = pack2(b.x, b.y); o.w = pack2(b.z, b.w);
        x0c[i] = o;
        return;
    }
    const int tid = threadIdx.x;
    const int e0 = blockIdx.x * CH;
    const int e1 = min(e0 + CH, E);
    for (int j = tid; j < 512; j += TB1) h[j] = 0;
    __syncthreads();
    int4 d[CH / (TB1 * 4)];
    int ngrp = 0;
    for (int i = e0 + tid * 4, k = 0; i < e1; i += TB1 * 4, ++k) {
        int4 t;
        if (i + 3 < e1) t = *(const int4*)(dst + i);
        else {
            t.x = dst[i];
            t.y = (i + 1 < e1) ? dst[i + 1] : -1;
            t.z = (i + 2 < e1) ? dst[i + 2] : -1;
            t.w = (i + 3 < e1) ? dst[i + 3] : -1;
        }
        d[k] = t;
        if (t.x >= 0) atomicAdd(&h[t.x >> GSH], 1);
        if (t.y >= 0) atomicAdd(&h[t.y >> GSH], 1);
        if (t.z >= 0) atomicAdd(&h[t.z >> GSH], 1);
        if (t.w >= 0) atomicAdd(&h[t.w >> GSH], 1);
        ngrp = k + 1;
    }
    __syncthreads();
    for (int j = tid; j < NB; j += TB1) {
        int c = h[j];
        h[j] = c ? atomicAdd(&cursor[j], c) : 0;
    }
    __syncthreads();
    for (int i = e0 + tid * 4, k = 0; k < ngrp; i += TB1 * 4, ++k) {
        int4 t = d[k];
        int4 ss = make_int4(0, 0, 0, 0);
        float4 ww = make_float4(0.f, 0.f, 0.f, 0.f);
        if (i + 3 < e1) { ss = *(const int4*)(src + i); ww = *(const float4*)(ew + i); }
        else {
            ss.x = src[i]; ww.x = ew[i];
            if (i + 1 < e1) { ss.y = src[i + 1]; ww.y = ew[i + 1]; }
            if (i + 2 < e1) { ss.z = src[i + 2]; ww.z = ew[i + 2]; }
            if (i + 3 < e1) { ss.w = src[i + 3]; ww.w = ew[i + 3]; }
        }
#define PART1(T, S, W) if ((T) >= 0) { \
        int pos_ = atomicAdd(&h[(T) >> GSH], 1); \
        staged[pos_] = make_int2((S) | (((T) & (GB - 1)) << 20), __float_as_int(W)); }
        PART1(t.x, ss.x, ww.x)
        PART1(t.y, ss.y, ww.y)
        PART1(t.z, ss.z, ww.z)
        PART1(t.w, ss.w, ww.w)
#undef PART1
    }
}

// ---- phase 2: per-bucket placement into final CSR + offsets -------------
__global__ void __launch_bounds__(256)
place_kernel(const int2* __restrict__ staged, const int* __restrict__ bucket_base,
             const float* __restrict__ dis,
             int* __restrict__ offsets, int2* __restrict__ csr, int N) {
    __shared__ int cnt[GB];
    __shared__ int cur[GB];
    __shared__ int pre[GB + 1];
    __shared__ float disb[GB];
    const int b = blockIdx.x;
    const int n0 = b << GSH;
    const int nb = min(GB, N - n0);
    const int r0 = bucket_base[b], r1 = bucket_base[b + 1];
    cnt[threadIdx.x] = 0;
    disb[threadIdx.x] = (threadIdx.x < nb) ? dis[n0 + threadIdx.x] : 0.f;
    __syncthreads();
    for (int i = r0 + threadIdx.x; i < r1; i += 256)
        atomicAdd(&cnt[(staged[i].x >> 20) & (GB - 1)], 1);
    __syncthreads();
    if (threadIdx.x == 0) {
        int run = r0;
        for (int j = 0; j < nb; ++j) { pre[j] = run; run += cnt[j]; }
        pre[nb] = run;
    }
    __syncthreads();
    if (threadIdx.x < nb) { offsets[n0 + threadIdx.x] = pre[threadIdx.x]; cur[threadIdx.x] = pre[threadIdx.x]; }
    __syncthreads();
    for (int i = r0 + threadIdx.x; i < r1; i += 256) {
        int2 rec = staged[i];
        int tl = (rec.x >> 20) & (GB - 1);
        int s = rec.x & 0xFFFFF;
        int rank = atomicAdd(&cur[tl], 1);
        float w = dis[s] * __int_as_float(rec.y) * disb[tl];
        csr[rank] = make_int2(s, __float_as_int(w));
    }
}

// ---- propagation (R4/R9-proven: bf16 gather, independent waves) ---------
// 8 nodes per wave: sub = lane>>3 -> node, fl = lane&7 -> 16B chunk of the
// 128B bf16 row. x8 unroll -> 64 row-gathers in flight per wave.
// Last layer (outF != null) fuses the final combine:
// out = 0.25*(emb + xa + xb + xc) with xc in full-precision registers.
__global__ void __launch_bounds__(256)
prop_kernel(const uint4* __restrict__ xg, const float4* __restrict__ selfF,
            uint4* __restrict__ xstore,
            const int* __restrict__ offsets, const int2* __restrict__ csr,
            const float* __restrict__ dis, int n,
            const float4* __restrict__ embF, const uint4* __restrict__ xaF,
            float4* __restrict__ outF) {
    const int lane = threadIdx.x & 63;
    const int fl  = lane & 7;
    const int sub = lane >> 3;
    const int wave = blockIdx.x * (blockDim.x >> 6) + (threadIdx.x >> 6);
    const int node = wave * 8 + sub;
    if (node >= n) return;

    const int beg = offsets[node];
    const int end = offsets[node + 1];
    const float d = dis[node];
    const float dd = d * d;   // self-loop: norm = dis[i]^2, weight 1

    float a0, a1, a2, a3, a4, a5, a6, a7;
    uint4 qs = make_uint4(0, 0, 0, 0);   // self row (kept for fused combine)
    if (selfF) {
        float4 s0 = selfF[(size_t)node * 16 + fl * 2];
        float4 s1 = selfF[(size_t)node * 16 + fl * 2 + 1];
        a0 = dd * s0.x; a1 = dd * s0.y; a2 = dd * s0.z; a3 = dd * s0.w;
        a4 = dd * s1.x; a5 = dd * s1.y; a6 = dd * s1.z; a7 = dd * s1.w;
    } else {
        qs = xg[(size_t)node * 8 + fl];
        float l, h;
        UNPK(qs.x, l, h) a0 = dd * l; a1 = dd * h;
        UNPK(qs.y, l, h) a2 = dd * l; a3 = dd * h;
        UNPK(qs.z, l, h) a4 = dd * l; a5 = dd * h;
        UNPK(qs.w, l, h) a6 = dd * l; a7 = dd * h;
    }

#define EDGE(E, Q) { float w_ = __int_as_float((E).y); float l, h; \
    UNPK((Q).x, l, h) a0 = fmaf(w_, l, a0); a1 = fmaf(w_, h, a1); \
    UNPK((Q).y, l, h) a2 = fmaf(w_, l, a2); a3 = fmaf(w_, h, a3); \
    UNPK((Q).z, l, h) a4 = fmaf(w_, l, a4); a5 = fmaf(w_, h, a5); \
    UNPK((Q).w, l, h) a6 = fmaf(w_, l, a6); a7 = fmaf(w_, h, a7); }

    int p = beg;
    for (; p + 8 <= end; p += 8) {
        int2 e0 = csr[p + 0], e1 = csr[p + 1], e2 = csr[p + 2], e3 = csr[p + 3];
        int2 e4 = csr[p + 4], e5 = csr[p + 5], e6 = csr[p + 6], e7 = csr[p + 7];
        uint4 q0 = xg[(size_t)e0.x * 8 + fl];
        uint4 q1 = xg[(size_t)e1.x * 8 + fl];
        uint4 q2 = xg[(size_t)e2.x * 8 + fl];
        uint4 q3 = xg[(size_t)e3.x * 8 + fl];
        uint4 q4 = xg[(size_t)e4.x * 8 + fl];
        uint4 q5 = xg[(size_t)e5.x * 8 + fl];
        uint4 q6 = xg[(size_t)e6.x * 8 + fl];
        uint4 q7 = xg[(size_t)e7.x * 8 + fl];
        EDGE(e0, q0) EDGE(e1, q1) EDGE(e2, q2) EDGE(e3, q3)
        EDGE(e4, q4) EDGE(e5, q5) EDGE(e6, q6) EDGE(e7, q7)
    }
    for (; p + 4 <= end; p += 4) {
        int2 e0 = csr[p + 0], e1 = csr[p + 1], e2 = csr[p + 2], e3 = csr[p + 3];
        uint4 q0 = xg[(size_t)e0.x * 8 + fl];
        uint4 q1 = xg[(size_t)e1.x * 8 + fl];
        uint4 q2 = xg[(size_t)e2.x * 8 + fl];
        uint4 q3 = xg[(size_t)e3.x * 8 + fl];
        EDGE(e0, q0) EDGE(e1, q1) EDGE(e2, q2) EDGE(e3, q3)
    }
    for (; p < end; ++p) {
        int2 e = csr[p];
        uint4 q = xg[(size_t)e.x * 8 + fl];
        EDGE(e, q)
    }
#undef EDGE

    if (outF) {
        // fused final combine: out = 0.25*(emb + xa + xb(=qs) + xc(regs))
        float4 eA = embF[(size_t)node * 16 + fl * 2];
        float4 eB = embF[(size_t)node * 16 + fl * 2 + 1];
        uint4 qa = xaF[(size_t)node * 8 + fl];
        float r0 = eA.x + a0, r1 = eA.y + a1, r2 = eA.z + a2, r3 = eA.w + a3;
        float r4 = eB.x + a4, r5 = eB.y + a5, r6 = eB.z + a6, r7 = eB.w + a7;
        float l, h;
        UNPK(qa.x, l, h) r0 += l; r1 += h;
        UNPK(qa.y, l, h) r2 += l; r3 += h;
        UNPK(qa.z, l, h) r4 += l; r5 += h;
        UNPK(qa.w, l, h) r6 += l; r7 += h;
        UNPK(qs.x, l, h) r0 += l; r1 += h;
        UNPK(qs.y, l, h) r2 += l; r3 += h;
        UNPK(qs.z, l, h) r4 += l; r5 += h;
        UNPK(qs.w, l, h) r6 += l; r7 += h;
        outF[(size_t)node * 16 + fl * 2] =
            make_float4(0.25f * r0, 0.25f * r1, 0.25f * r2, 0.25f * r3);
        outF[(size_t)node * 16 + fl * 2 + 1] =
            make_float4(0.25f * r4, 0.25f * r5, 0.25f * r6, 0.25f * r7);
    } else {
        uint4 o;
        o.x = pack2(a0, a1); o.y = pack2(a2, a3);
        o.z = pack2(a4, a5); o.w = pack2(a6, a7);
        xstore[(size_t)node * 8 + fl] = o;
    }
}

// ---- launch -------------------------------------------------------------

extern "C" void kernel_launch(void* const* d_in, const int* in_sizes, int n_in,
                              void* d_out, int out_size, void* d_ws, size_t ws_size,
                              hipStream_t stream) {
    const float* emb = (const float*)d_in[0];   // [N, 64] fp32
    const float* ew  = (const float*)d_in[1];   // [E] fp32
    const int*   ei  = (const int*)d_in[2];     // [2, E] int32
    const int E = in_sizes[2] / 2;
    const int N = in_sizes[0] / DIM;
    const int* src = ei;        // edge_index[0] = source j
    const int* dst = ei + E;    // edge_index[1] = target i
    float* out = (float*)d_out;

    const int NB = (N + GB - 1) >> GSH;   // dst buckets (391 @ N=100k)
    const int Es = (E + NSL - 1) / NSL;   // edges per hist slice
    const int nw = (N + 3) >> 2;          // u8 hist words per slice

    // workspace (~80 MB). Alias chain on one region (sequentially dead):
    //   partials (25.6 MB, dead after merge_scan) -> staged (dead after
    //   place) -> xb (first written in prop L2)
    char* w = (char*)d_ws;
    size_t xSz = ((size_t)N * DIM * 2 + 255) & ~(size_t)255;       // 12.8 MB
    size_t sSz = ((size_t)E * 8 + 255) & ~(size_t)255;             // 12.8 MB
    size_t pSz = ((size_t)NSL * nw * 4 + 255) & ~(size_t)255;      // 25.6 MB
    size_t uSz = xSz > sSz ? xSz : sSz; if (pSz > uSz) uSz = pSz;
    unsigned* partials = (unsigned*)w;
    int2* staged = (int2*)w;
    uint4* xb    = (uint4*)w; w += uSz;
    int2* csr    = (int2*)w; w += sSz;
    uint4* x0c   = (uint4*)w; w += xSz;   // bf16 emb copy
    uint4* xa    = (uint4*)w; w += xSz;   // bf16 layer-1 x
    int* offsets = (int*)w; w += ((size_t)(N + 1) * 4 + 255) & ~(size_t)255;
    float* dis   = (float*)w; w += ((size_t)N * 4 + 255) & ~(size_t)255;
    int* bslice      = (int*)w; w += (size_t)NSL * 512 * 4;   // 512 KB
    int* bucket_base = (int*)w; w += 513 * 4;
    int* cursor      = (int*)w; w += 512 * 4;

    const int TB = 256;

    hist_kernel<<<NSL, TBH, 0, stream>>>(src, dst, partials, bslice, E, N, Es, NB);

    const int nmerge = (nw + 511) / 512;
    merge_scan_kernel<<<nmerge + 1, 512, 0, stream>>>(partials, bslice, dis,
                                                      bucket_base, cursor, offsets,
                                                      nw, nmerge, N, NB);

    const int n8 = N * DIM / 8;
    const int npart = (E + CH - 1) / CH;
    const int nconv = (n8 + TB - 1) / TB;
    part_conv_kernel<<<npart + nconv, TB1, 0, stream>>>(src, dst, ew, cursor, staged,
                                                        (const float4*)emb, x0c,
                                                        E, NB, npart, n8);
    place_kernel<<<NB, TB, 0, stream>>>(staged, bucket_base, dis, offsets, csr, N);

    // 4 waves/block, 8 nodes/wave -> 32 nodes per block
    dim3 grid((N + 31) / 32), block(TB);
    prop_kernel<<<grid, block, 0, stream>>>(x0c, (const float4*)emb, xa,
                                            offsets, csr, dis, N,
                                            nullptr, nullptr, nullptr);
    prop_kernel<<<grid, block, 0, stream>>>(xa, nullptr, xb,
                                            offsets, csr, dis, N,
                                            nullptr, nullptr, nullptr);
    prop_kernel<<<grid, block, 0, stream>>>(xb, nullptr, nullptr,
                                            offsets, csr, dis, N,
                                            (const float4*)emb, xa, (float4*)out);
}